// Round 7
// baseline (2606.548 us; speedup 1.0000x reference)
//
#include <hip/hip_runtime.h>
#include <math.h>

#define NB 8
#define NS 256
#define NH 768
#define NL 20
#define NT 8
#define NE 300
#define NEGV (-10000.0f)
#define BS_ (NB*NS)          // 2048
#define NLT (NL*NT)          // 160

__device__ __forceinline__ float fast_tanh(float x) {
  float e = __expf(2.0f * x);
  return 1.0f - 2.0f / (e + 1.0f);
}

// ---------------------------------------------------------------------------
// f32 GEMM: C[m,n] = sum_k A[m,k] * B[n,k].  64x64 tile, BK=16, 4x4 micro.
// M,N multiples of 64; K multiple of 16.  Pure VALU (no MFMA).
// ---------------------------------------------------------------------------
__global__ __launch_bounds__(256)
void gemm64(const float* __restrict__ A, int lda,
            const float* __restrict__ B, int ldb, int K,
            float* __restrict__ C, int ldc)
{
  __shared__ float As[16][64];   // [k][m]
  __shared__ float Bs[16][64];   // [k][n]
  const int t  = threadIdx.x;
  const int bm = blockIdx.x * 64, bn = blockIdx.y * 64;
  const int tm = t & 15, tn = t >> 4;
  const int lr = t >> 2;         // 0..63: row being loaded
  const int lk = (t & 3) * 4;    // k0 of float4
  float acc[4][4];
#pragma unroll
  for (int r = 0; r < 4; r++)
#pragma unroll
    for (int c = 0; c < 4; c++) acc[r][c] = 0.f;

  for (int kt = 0; kt < K; kt += 16) {
    float4 a4 = *(const float4*)(A + (size_t)(bm + lr) * lda + kt + lk);
    float4 b4 = *(const float4*)(B + (size_t)(bn + lr) * ldb + kt + lk);
    As[lk+0][lr] = a4.x; As[lk+1][lr] = a4.y; As[lk+2][lr] = a4.z; As[lk+3][lr] = a4.w;
    Bs[lk+0][lr] = b4.x; Bs[lk+1][lr] = b4.y; Bs[lk+2][lr] = b4.z; Bs[lk+3][lr] = b4.w;
    __syncthreads();
#pragma unroll
    for (int k = 0; k < 16; k++) {
      float av[4], bv[4];
#pragma unroll
      for (int r = 0; r < 4; r++) av[r] = As[k][tm*4 + r];
#pragma unroll
      for (int c = 0; c < 4; c++) bv[c] = Bs[k][tn*4 + c];
#pragma unroll
      for (int r = 0; r < 4; r++)
#pragma unroll
        for (int c = 0; c < 4; c++) acc[r][c] += av[r] * bv[c];
    }
    __syncthreads();
  }
#pragma unroll
  for (int r = 0; r < 4; r++)
#pragma unroll
    for (int c = 0; c < 4; c++)
      C[(size_t)(bm + tm*4 + r) * ldc + bn + tn*4 + c] = acc[r][c];
}

// lab[lt,o] = sum_e label[lt,e] * W2[o,e]     (160 x 768, K=300)
__global__ __launch_bounds__(256)
void lab_kernel(const float* __restrict__ label, const float* __restrict__ W2,
                float* __restrict__ lab)
{
  int lt = blockIdx.x;
  __shared__ float le[NE];
  for (int e = threadIdx.x; e < NE; e += 256) le[e] = label[(size_t)lt*NE + e];
  __syncthreads();
  for (int o = threadIdx.x; o < NH; o += 256) {
    const float* wr = W2 + (size_t)o*NE;
    float s = 0.f;
    for (int e = 0; e < NE; e++) s += le[e] * wr[e];
    lab[(size_t)lt*NH + o] = s;
  }
}

// LB[lt,o] = sum_h lab[lt,h] * W5[o, 768+h]
__global__ __launch_bounds__(256)
void LB_kernel(const float* __restrict__ lab, const float* __restrict__ W5,
               float* __restrict__ LB)
{
  int lt = blockIdx.x;
  __shared__ float lr[NH];
  for (int h = threadIdx.x; h < NH; h += 256) lr[h] = lab[(size_t)lt*NH + h];
  __syncthreads();
  for (int o = threadIdx.x; o < NH; o += 256) {
    const float* wr = W5 + (size_t)o*3072 + NH;
    float s = 0.f;
    for (int h = 0; h < NH; h++) s += lr[h] * wr[h];
    LB[(size_t)lt*NH + o] = s;
  }
}

// scores + softmax over label tokens; a-weights and masked row-max (b_in)
__global__ __launch_bounds__(256)
void scores_kernel(const float* __restrict__ tkn, const float* __restrict__ lab,
                   const float* __restrict__ lmask, const float* __restrict__ imask,
                   float* __restrict__ aw, float* __restrict__ b_in)
{
  int bs = blockIdx.x;
  __shared__ float trow[NH];
  __shared__ float sc[NLT];
  __shared__ float mL[NL], iL[NL];
  for (int h = threadIdx.x; h < NH; h += 256) trow[h] = tkn[(size_t)bs*NH + h];
  __syncthreads();
  int j = threadIdx.x;
  if (j < NLT) {
    const float* lrow = lab + (size_t)j*NH;
    float s = 0.f;
    for (int h = 0; h < NH; h++) s += trow[h] * lrow[h];
    s += (1.0f - lmask[j]) * NEGV;
    sc[j] = s;
  }
  __syncthreads();
  if (j < NL) {
    float m = sc[j*8];
    for (int t = 1; t < 8; t++) m = fmaxf(m, sc[j*8 + t]);
    float ssum = 0.f;
    for (int t = 0; t < 8; t++) ssum += __expf(sc[j*8 + t] - m);
    mL[j] = m; iL[j] = 1.0f / ssum;
    b_in[(size_t)bs*NL + j] = m + (1.0f - imask[bs]) * NEGV;
  }
  __syncthreads();
  if (j < NLT) aw[(size_t)bs*NLT + j] = __expf(sc[j] - mL[j >> 3]) * iL[j >> 3];
}

// softmax over S per (b,l)
__global__ __launch_bounds__(256)
void softs_kernel(const float* __restrict__ b_in, float* __restrict__ bc)
{
  int b = blockIdx.x / NL, l = blockIdx.x % NL;
  int s = threadIdx.x;
  __shared__ float red[256];
  float v = b_in[((size_t)b*NS + s)*NL + l];
  red[s] = v; __syncthreads();
  for (int off = 128; off > 0; off >>= 1) {
    if (s < off) red[s] = fmaxf(red[s], red[s + off]);
    __syncthreads();
  }
  float m = red[0]; __syncthreads();
  float e = __expf(v - m);
  red[s] = e; __syncthreads();
  for (int off = 128; off > 0; off >>= 1) {
    if (s < off) red[s] += red[s + off];
    __syncthreads();
  }
  bc[((size_t)b*NS + s)*NL + l] = e / red[0];
}

// q2c[b,l,h] = sum_s bc[b,s,l] * tkn[b,s,h]
__global__ __launch_bounds__(256)
void q2c_kernel(const float* __restrict__ bc, const float* __restrict__ tkn,
                float* __restrict__ q2c)
{
  int b = blockIdx.x / NL, l = blockIdx.x % NL;
  __shared__ float bl[NS];
  bl[threadIdx.x] = bc[((size_t)b*NS + threadIdx.x)*NL + l];
  __syncthreads();
  for (int h = threadIdx.x; h < NH; h += 256) {
    float s = 0.f;
    for (int sx = 0; sx < NS; sx++) s += bl[sx] * tkn[((size_t)b*NS + sx)*NH + h];
    q2c[((size_t)(b*NL + l))*NH + h] = s;
  }
}

// ---------------------------------------------------------------------------
// Fused output: block = (b, l, s-tile 64) x (o-tile 64).  Builds
// A1 = tkn .* c2q, A2 = tkn .* q2c on the fly in LDS (k-major), GEMMs against
// W5 blocks 3/4, epilogue adds T1 + sum_t aw*LB + b5, tanh, f32 store.
// ---------------------------------------------------------------------------
__global__ __launch_bounds__(256)
void fused_out(const float* __restrict__ tkn, const float* __restrict__ lab,
               const float* __restrict__ aw, const float* __restrict__ q2c,
               const float* __restrict__ T1, const float* __restrict__ LB,
               const float* __restrict__ W5, const float* __restrict__ b5,
               float* __restrict__ outp)
{
  const int t  = threadIdx.x;
  const int sq = blockIdx.x & 3;             // s-tile (NS/64 = 4)
  const int l  = (blockIdx.x >> 2) % NL;
  const int b  = blockIdx.x / (4 * NL);
  const int o0 = blockIdx.y * 64;
  const int s0 = sq * 64;
  const int tm = t & 15, tn = t >> 4;
  const int lr = t >> 2;                     // 0..63
  const int lk = (t & 3) * 4;                // 0,4,8,12

  __shared__ float A1s[16][64];              // [k][m]  tkn*c2q
  __shared__ float A2s[16][64];              // [k][m]  tkn*q2c
  __shared__ float Cs[16][64];               // [k][n]  W5 block 3
  __shared__ float Ds[16][64];               // [k][n]  W5 block 4
  __shared__ float labS[NT][16];
  __shared__ float q2cS[16];
  __shared__ float awS[64][NT];
  __shared__ float LBS[NT][64];
  __shared__ float b5S[64];

  for (int i = t; i < 64*NT; i += 256) {
    int m = i >> 3, tt = i & 7;
    awS[m][tt] = aw[(size_t)(b*NS + s0 + m) * NLT + l*NT + tt];
  }
  for (int i = t; i < NT*64; i += 256) {
    int tt = i >> 6, n = i & 63;
    LBS[tt][n] = LB[(size_t)(l*NT + tt) * NH + o0 + n];
  }
  if (t < 64) b5S[t] = b5[o0 + t];

  float acc[4][4];
#pragma unroll
  for (int r = 0; r < 4; r++)
#pragma unroll
    for (int c = 0; c < 4; c++) acc[r][c] = 0.f;

  for (int kt = 0; kt < NH; kt += 16) {
    // phase 1: stage lab slice, q2c slice, W5 tiles
    if (t < 128) { int tt = t >> 4, k = t & 15; labS[tt][k] = lab[(size_t)(l*NT + tt)*NH + kt + k]; }
    if (t < 16)  q2cS[t] = q2c[(size_t)(b*NL + l)*NH + kt + t];
    {
      float4 c4 = *(const float4*)(W5 + (size_t)(o0 + lr)*3072 + 1536 + kt + lk);
      Cs[lk+0][lr] = c4.x; Cs[lk+1][lr] = c4.y; Cs[lk+2][lr] = c4.z; Cs[lk+3][lr] = c4.w;
      float4 d4 = *(const float4*)(W5 + (size_t)(o0 + lr)*3072 + 2304 + kt + lk);
      Ds[lk+0][lr] = d4.x; Ds[lk+1][lr] = d4.y; Ds[lk+2][lr] = d4.z; Ds[lk+3][lr] = d4.w;
    }
    __syncthreads();
    // phase 2: build A1s/A2s for m = lr, k = lk..lk+3
    {
      float4 t4 = *(const float4*)(tkn + (size_t)(b*NS + s0 + lr)*NH + kt + lk);
      float tv[4] = {t4.x, t4.y, t4.z, t4.w};
#pragma unroll
      for (int j = 0; j < 4; j++) {
        int k = lk + j;
        float c2 = 0.f;
#pragma unroll
        for (int tt = 0; tt < NT; tt++) c2 += awS[lr][tt] * labS[tt][k];
        A1s[k][lr] = tv[j] * c2;
        A2s[k][lr] = tv[j] * q2cS[k];
      }
    }
    __syncthreads();
    // phase 3: GEMM inner
#pragma unroll
    for (int k = 0; k < 16; k++) {
      float a1[4], a2[4], wc[4], wd[4];
#pragma unroll
      for (int r = 0; r < 4; r++) { a1[r] = A1s[k][tm*4 + r]; a2[r] = A2s[k][tm*4 + r]; }
#pragma unroll
      for (int c = 0; c < 4; c++) { wc[c] = Cs[k][tn*4 + c]; wd[c] = Ds[k][tn*4 + c]; }
#pragma unroll
      for (int r = 0; r < 4; r++)
#pragma unroll
        for (int c = 0; c < 4; c++)
          acc[r][c] += a1[r]*wc[c] + a2[r]*wd[c];
    }
    __syncthreads();
  }

  // epilogue — f32 output
#pragma unroll
  for (int r = 0; r < 4; r++) {
    int m = tm*4 + r;
    int s = s0 + m;
    size_t orow = ((size_t)(b*NS + s)*NL + l)*NH + o0;
    const float* T1r = T1 + (size_t)(b*NS + s)*NH + o0;
#pragma unroll
    for (int c = 0; c < 4; c++) {
      int n = tn*4 + c;
      float v = acc[r][c] + T1r[n] + b5S[n];
#pragma unroll
      for (int tt = 0; tt < NT; tt++) v += awS[m][tt] * LBS[tt][n];
      outp[orow + n] = fast_tanh(v);
    }
  }
}

extern "C" void kernel_launch(void* const* d_in, const int* in_sizes, int n_in,
                              void* d_out, int out_size, void* d_ws, size_t ws_size,
                              hipStream_t stream)
{
  const float* token = (const float*)d_in[0];
  const float* label = (const float*)d_in[1];
  const float* imask = (const float*)d_in[2];
  const float* lmask = (const float*)d_in[3];
  const float* W1    = (const float*)d_in[4];
  const float* W2    = (const float*)d_in[5];
  const float* W5    = (const float*)d_in[6];
  const float* b5    = (const float*)d_in[7];
  float* outp = (float*)d_out;

  // ---- workspace head: ~15.7 MB, all f32 ----
  char* p = (char*)d_ws;
  float* tkn  = (float*)p; p += (size_t)BS_*NH*4;     // 6,291,456
  float* T1   = (float*)p; p += (size_t)BS_*NH*4;     // 6,291,456
  float* lab  = (float*)p; p += (size_t)NLT*NH*4;     //   491,520
  float* LB   = (float*)p; p += (size_t)NLT*NH*4;     //   491,520
  float* aw   = (float*)p; p += (size_t)BS_*NLT*4;    // 1,310,720
  float* b_in = (float*)p; p += (size_t)BS_*NL*4;     //   163,840
  float* bc   = (float*)p; p += (size_t)BS_*NL*4;     //   163,840
  float* q2c  = (float*)p; p += (size_t)NL*NB*NH*4;   //   491,520

  // tkn[bs,o] = sum_h token[bs,h] * W1[o,h]
  gemm64<<<dim3(BS_/64, NH/64), 256, 0, stream>>>(token, NH, W1, NH, NH, tkn, NH);
  lab_kernel<<<NLT, 256, 0, stream>>>(label, W2, lab);
  // T1[bs,o] = sum_h tkn[bs,h] * W5[o,h]   (W5 block 1)
  gemm64<<<dim3(BS_/64, NH/64), 256, 0, stream>>>(tkn, NH, W5, 3072, NH, T1, NH);
  LB_kernel<<<NLT, 256, 0, stream>>>(lab, W5, LB);
  scores_kernel<<<BS_, 256, 0, stream>>>(tkn, lab, lmask, imask, aw, b_in);
  softs_kernel<<<NB*NL, 256, 0, stream>>>(b_in, bc);
  q2c_kernel<<<NB*NL, 256, 0, stream>>>(bc, tkn, q2c);
  fused_out<<<dim3(NB*NL*4, NH/64), 256, 0, stream>>>(tkn, lab, aw, q2c, T1, LB, W5, b5, outp);
}